// Round 11
// baseline (120.959 us; speedup 1.0000x reference)
//
#include <hip/hip_runtime.h>

#define D    300
#define NF4  75            // 300 floats = 75 float4 per row
#define K    10
#define WPB  4             // waves per block
#define GPB  16            // 16-lane row-groups per block
#define NBLOCKS 2048
#define NGROUPS (NBLOCKS * GPB)   // 32768

#define NCAND      (NBLOCKS * K)     // 20480
#define F_THREADS  1024
#define F_CPT      20                // NCAND / F_THREADS

typedef float f32x4 __attribute__((ext_vector_type(4)));

__device__ __forceinline__ f32x4 ntload(const f32x4* p) {
    return __builtin_nontemporal_load(p);
}

__device__ __forceinline__ float d4(f32x4 a, f32x4 b) {
    return a[0]*b[0] + a[1]*b[1] + a[2]*b[2] + a[3]*b[3];
}

#define RED16(x) { x += __shfl_xor(x, 8, 64); x += __shfl_xor(x, 4, 64); \
                   x += __shfl_xor(x, 2, 64); x += __shfl_xor(x, 1, 64); }

// -------- Phase 1: cosine + per-group top-10, fused (no score array) --------
// 16 lanes per row, 4 consecutive rows per wave, strided groups, alternating
// temporal / non-temporal loads (best measured mixed read policy).
__global__ __launch_bounds__(256) void cos_topk(
    const float* __restrict__ emb, const float* __restrict__ wvec,
    float* __restrict__ cand_v, int* __restrict__ cand_i,
    int V, int s)
{
    const int tid  = threadIdx.x;
    const int lane = tid & 63;
    const int wid  = tid >> 6;
    const int l16  = lane & 15;
    const int rg   = lane >> 4;
    const bool tl  = (l16 < NF4 - 64);     // 11 tail lanes

    const f32x4* w4p = (const f32x4*)wvec;
    f32x4 w0 = w4p[l16];
    f32x4 w1 = w4p[l16 + 16];
    f32x4 w2 = w4p[l16 + 32];
    f32x4 w3 = w4p[l16 + 48];
    f32x4 w4t = 0.f;
    if (tl) w4t = w4p[l16 + 64];

    float qsq = d4(w0,w0)+d4(w1,w1)+d4(w2,w2)+d4(w3,w3)+d4(w4t,w4t);
    RED16(qsq);
    const float qn = sqrtf(qsq);

    // per-group top-10 (values group-uniform after RED16 -> uniform branch)
    float tv[K]; int ti[K];
    #pragma unroll
    for (int j = 0; j < K; ++j) { tv[j] = -3e38f; ti[j] = 0; }

    const int g0 = (blockIdx.x * WPB + wid) * 4 + rg;
    const size_t stepF4 = (size_t)s * NF4;
    const f32x4* p = (const f32x4*)emb + (size_t)g0 * NF4 + l16;

#define BODY(a0,a1,a2,a3,a4, ROW)                                \
    {   float da = d4(a0,w0) + d4(a1,w1);                        \
        float db = d4(a2,w2) + d4(a3,w3) + d4(a4,w4t);           \
        float sa = d4(a0,a0) + d4(a1,a1);                        \
        float sb = d4(a2,a2) + d4(a3,a3) + d4(a4,a4);            \
        float dot = da + db;                                     \
        float sq  = sa + sb;                                     \
        RED16(dot); RED16(sq);                                   \
        float c = dot / (sqrtf(sq + 1e-9f) * qn);                \
        if (c > tv[K-1]) {                                       \
            tv[K-1] = c; ti[K-1] = (ROW);                        \
            _Pragma("unroll")                                    \
            for (int j = K-1; j > 0; --j) {                      \
                if (tv[j] > tv[j-1]) {                           \
                    float t = tv[j]; tv[j] = tv[j-1]; tv[j-1] = t;\
                    int   u = ti[j]; ti[j] = ti[j-1]; ti[j-1] = u;\
                }                                                \
            }                                                    \
        }                                                        \
    }

    int r = g0;
    while (r < V) {
        {   // temporal (L2-allocate path)
            f32x4 a0 = p[0];
            f32x4 a1 = p[16];
            f32x4 a2 = p[32];
            f32x4 a3 = p[48];
            f32x4 a4 = 0.f;
            if (tl) a4 = p[64];
            BODY(a0,a1,a2,a3,a4, r)
            r += s; p += stepF4;
        }
        if (r < V) {   // non-temporal (bypass path)
            f32x4 a0 = ntload(p);
            f32x4 a1 = ntload(p + 16);
            f32x4 a2 = ntload(p + 32);
            f32x4 a3 = ntload(p + 48);
            f32x4 a4 = 0.f;
            if (tl) a4 = ntload(p + 64);
            BODY(a0,a1,a2,a3,a4, r)
            r += s; p += stepF4;
        }
    }
#undef BODY

    // merge the block's 16 groups in LDS -> block top-10
    __shared__ float sv[GPB * K];
    __shared__ int   si[GPB * K];
    if (l16 == 0) {
        const int gidx = wid * 4 + rg;
        #pragma unroll
        for (int j = 0; j < K; ++j) { sv[gidx*K + j] = tv[j]; si[gidx*K + j] = ti[j]; }
    }
    __syncthreads();
    if (tid == 0) {
        float bv[K]; int bi[K];
        #pragma unroll
        for (int j = 0; j < K; ++j) { bv[j] = -3e38f; bi[j] = 0; }
        for (int t = 0; t < GPB * K; ++t) {
            float c = sv[t]; int rr = si[t];
            if (c > bv[K-1]) {
                bv[K-1] = c; bi[K-1] = rr;
                #pragma unroll
                for (int j = K-1; j > 0; --j) {
                    if (bv[j] > bv[j-1]) {
                        float t2 = bv[j]; bv[j] = bv[j-1]; bv[j-1] = t2;
                        int   u2 = bi[j]; bi[j] = bi[j-1]; bi[j-1] = u2;
                    }
                }
            }
        }
        #pragma unroll
        for (int j = 0; j < K; ++j) {
            cand_v[blockIdx.x*K + j] = bv[j];
            cand_i[blockIdx.x*K + j] = bi[j];
        }
    }
}

// ---------------- Phase 2: final top-10 over 20480 candidates ----------------
__global__ __launch_bounds__(F_THREADS) void final_topk(
    const float* __restrict__ cand_v, const int* __restrict__ cand_i,
    float* __restrict__ out)
{
    __shared__ float rv[16];
    __shared__ int   rp[16];
    __shared__ int   s_bp;

    const int tid  = threadIdx.x;
    const int lane = tid & 63;
    const int wid  = tid >> 6;

    float v[F_CPT];
    #pragma unroll
    for (int t = 0; t < F_CPT; ++t) v[t] = cand_v[tid + t * F_THREADS];

    for (int p = 0; p < K; ++p) {
        float bestv = -3e38f; int bestpos = 0x7fffffff;
        #pragma unroll
        for (int t = 0; t < F_CPT; ++t) {
            if (v[t] > bestv) { bestv = v[t]; bestpos = tid + t * F_THREADS; }
        }
        #pragma unroll
        for (int m = 32; m >= 1; m >>= 1) {
            float ov = __shfl_xor(bestv, m, 64);
            int   op = __shfl_xor(bestpos, m, 64);
            if (ov > bestv || (ov == bestv && op < bestpos)) { bestv = ov; bestpos = op; }
        }
        if (lane == 0) { rv[wid] = bestv; rp[wid] = bestpos; }
        __syncthreads();
        if (tid == 0) {
            float bv = rv[0]; int bp = rp[0];
            for (int i = 1; i < 16; ++i)
                if (rv[i] > bv || (rv[i] == bv && rp[i] < bp)) { bv = rv[i]; bp = rp[i]; }
            out[p]     = bv;
            out[K + p] = (float)cand_i[bp];     // exact < 2^24
            s_bp = bp;
        }
        __syncthreads();
        const int wbp = s_bp;
        #pragma unroll
        for (int t = 0; t < F_CPT; ++t) {
            if (tid + t * F_THREADS == wbp) v[t] = -3e38f;
        }
        __syncthreads();
    }
}

extern "C" void kernel_launch(void* const* d_in, const int* in_sizes, int n_in,
                              void* d_out, int out_size, void* d_ws, size_t ws_size,
                              hipStream_t stream) {
    const float* emb  = (const float*)d_in[0];
    const float* wvec = (const float*)d_in[1];
    const int V = in_sizes[0] / D;

    float* cand_v = (float*)d_ws;
    int*   cand_i = (int*)(cand_v + NCAND);

    cos_topk<<<NBLOCKS, 256, 0, stream>>>(emb, wvec, cand_v, cand_i, V, NGROUPS);
    final_topk<<<1, F_THREADS, 0, stream>>>(cand_v, cand_i, (float*)d_out);
}

// Round 12
// 119.614 us; speedup vs baseline: 1.0112x; 1.0112x over previous
//
#include <hip/hip_runtime.h>

#define D    300
#define NF4  75            // 300 floats = 75 float4 per row
#define K    10
#define WPB  4             // waves per block
#define GPB  16            // 16-lane row-groups per block
#define NBLOCKS 2048
#define NGROUPS (NBLOCKS * GPB)   // 32768
#define RA_ROWS (5 * NGROUPS)     // 163840 rows: temporal region (~197MB)

#define P2_BLOCKS  256
#define P2_THREADS 1024
#define P2_CPT     2       // ceil(400000/256/1024)
#define NCAND      (P2_BLOCKS * K)   // 2560
#define F_CPT      3       // ceil(2560/1024)

typedef float f32x4 __attribute__((ext_vector_type(4)));

__device__ __forceinline__ f32x4 ntload(const f32x4* p) {
    return __builtin_nontemporal_load(p);
}

__device__ __forceinline__ float d4(f32x4 a, f32x4 b) {
    return a[0]*b[0] + a[1]*b[1] + a[2]*b[2] + a[3]*b[3];
}

#define RED16(x) { x += __shfl_xor(x, 8, 64); x += __shfl_xor(x, 4, 64); \
                   x += __shfl_xor(x, 2, 64); x += __shfl_xor(x, 1, 64); }

// ---------------- Phase 1: cosine for ALL rows -> score[] ----------------
// 16 lanes per row, 4 consecutive rows per wave, strided groups.
// Region A (first RA rows): temporal loads; Region B: non-temporal.
// (Best measured read policy: 119.4us total, vs 122 NT-only, 133 plain.)
__global__ __launch_bounds__(256) void cos_all(
    const float* __restrict__ emb, const float* __restrict__ wvec,
    float* __restrict__ score, int V, int s, int RA)
{
    const int tid  = threadIdx.x;
    const int lane = tid & 63;
    const int wid  = tid >> 6;
    const int l16  = lane & 15;
    const int rg   = lane >> 4;
    const bool tl  = (l16 < NF4 - 64);     // 11 tail lanes

    const f32x4* w4p = (const f32x4*)wvec;
    f32x4 w0 = w4p[l16];
    f32x4 w1 = w4p[l16 + 16];
    f32x4 w2 = w4p[l16 + 32];
    f32x4 w3 = w4p[l16 + 48];
    f32x4 w4t = 0.f;
    if (tl) w4t = w4p[l16 + 64];

    float qsq = d4(w0,w0)+d4(w1,w1)+d4(w2,w2)+d4(w3,w3)+d4(w4t,w4t);
    RED16(qsq);
    const float qn = sqrtf(qsq);

    const int g0 = (blockIdx.x * WPB + wid) * 4 + rg;
    const size_t stepF4 = (size_t)s * NF4;

    const f32x4* p = (const f32x4*)emb + (size_t)g0 * NF4 + l16;

#define BODY(a0,a1,a2,a3,a4, ROW)                            \
    {   float da = d4(a0,w0) + d4(a1,w1);                    \
        float db = d4(a2,w2) + d4(a3,w3) + d4(a4,w4t);       \
        float sa = d4(a0,a0) + d4(a1,a1);                    \
        float sb = d4(a2,a2) + d4(a3,a3) + d4(a4,a4);        \
        float dot = da + db;                                 \
        float sq  = sa + sb;                                 \
        RED16(dot); RED16(sq);                               \
        float c = dot / (sqrtf(sq + 1e-9f) * qn);            \
        if (l16 == 0) score[ROW] = c; }

    int r = g0;
    // --- Region A: temporal loads ---
    for (; r < RA; r += s, p += stepF4) {
        f32x4 a0 = p[0];
        f32x4 a1 = p[16];
        f32x4 a2 = p[32];
        f32x4 a3 = p[48];
        f32x4 a4 = 0.f;
        if (tl) a4 = p[64];
        BODY(a0,a1,a2,a3,a4, r)
    }
    // --- Region B: non-temporal loads ---
    for (; r < V; r += s, p += stepF4) {
        f32x4 a0 = ntload(p);
        f32x4 a1 = ntload(p + 16);
        f32x4 a2 = ntload(p + 32);
        f32x4 a3 = ntload(p + 48);
        f32x4 a4 = 0.f;
        if (tl) a4 = ntload(p + 64);
        BODY(a0,a1,a2,a3,a4, r)
    }
#undef BODY
}

// ---------------- Phase 2a: exact per-block top-10 over score chunks ----------------
__global__ __launch_bounds__(P2_THREADS) void block_topk(
    const float* __restrict__ score, int V,
    float* __restrict__ cand_v, int* __restrict__ cand_i)
{
    __shared__ float rv[16];
    __shared__ int   rp[16];
    __shared__ int   s_bp;

    const int tid  = threadIdx.x;
    const int lane = tid & 63;
    const int wid  = tid >> 6;
    const int per  = (V + P2_BLOCKS - 1) / P2_BLOCKS;
    const int base = blockIdx.x * per;

    float v[P2_CPT];
    #pragma unroll
    for (int t = 0; t < P2_CPT; ++t) {
        int i = tid + t * P2_THREADS;
        v[t] = (i < per && base + i < V) ? score[base + i] : -3e38f;
    }

    for (int p = 0; p < K; ++p) {
        float bestv = -3e38f; int bestpos = 0x7fffffff;
        #pragma unroll
        for (int t = 0; t < P2_CPT; ++t) {
            if (v[t] > bestv) { bestv = v[t]; bestpos = tid + t * P2_THREADS; }
        }
        #pragma unroll
        for (int m = 32; m >= 1; m >>= 1) {
            float ov = __shfl_xor(bestv, m, 64);
            int   op = __shfl_xor(bestpos, m, 64);
            if (ov > bestv || (ov == bestv && op < bestpos)) { bestv = ov; bestpos = op; }
        }
        if (lane == 0) { rv[wid] = bestv; rp[wid] = bestpos; }
        __syncthreads();
        if (tid == 0) {
            float bv = rv[0]; int bp = rp[0];
            for (int i = 1; i < 16; ++i)
                if (rv[i] > bv || (rv[i] == bv && rp[i] < bp)) { bv = rv[i]; bp = rp[i]; }
            cand_v[blockIdx.x*K + p] = bv;
            cand_i[blockIdx.x*K + p] = base + bp;
            s_bp = bp;
        }
        __syncthreads();
        const int wbp = s_bp;
        #pragma unroll
        for (int t = 0; t < P2_CPT; ++t) {
            if (tid + t * P2_THREADS == wbp) v[t] = -3e38f;
        }
        __syncthreads();
    }
}

// ---------------- Phase 2b: final top-10 over 2560 candidates ----------------
__global__ __launch_bounds__(P2_THREADS) void final_topk(
    const float* __restrict__ cand_v, const int* __restrict__ cand_i,
    float* __restrict__ out)
{
    __shared__ float rv[16];
    __shared__ int   rp[16];
    __shared__ int   s_bp;

    const int tid  = threadIdx.x;
    const int lane = tid & 63;
    const int wid  = tid >> 6;

    float v[F_CPT];
    #pragma unroll
    for (int t = 0; t < F_CPT; ++t) {
        int i = tid + t * P2_THREADS;
        v[t] = (i < NCAND) ? cand_v[i] : -3e38f;
    }

    for (int p = 0; p < K; ++p) {
        float bestv = -3e38f; int bestpos = 0x7fffffff;
        #pragma unroll
        for (int t = 0; t < F_CPT; ++t) {
            if (v[t] > bestv) { bestv = v[t]; bestpos = tid + t * P2_THREADS; }
        }
        #pragma unroll
        for (int m = 32; m >= 1; m >>= 1) {
            float ov = __shfl_xor(bestv, m, 64);
            int   op = __shfl_xor(bestpos, m, 64);
            if (ov > bestv || (ov == bestv && op < bestpos)) { bestv = ov; bestpos = op; }
        }
        if (lane == 0) { rv[wid] = bestv; rp[wid] = bestpos; }
        __syncthreads();
        if (tid == 0) {
            float bv = rv[0]; int bp = rp[0];
            for (int i = 1; i < 16; ++i)
                if (rv[i] > bv || (rv[i] == bv && rp[i] < bp)) { bv = rv[i]; bp = rp[i]; }
            out[p]     = bv;
            out[K + p] = (float)cand_i[bp];     // exact < 2^24
            s_bp = bp;
        }
        __syncthreads();
        const int wbp = s_bp;
        #pragma unroll
        for (int t = 0; t < F_CPT; ++t) {
            if (tid + t * P2_THREADS == wbp) v[t] = -3e38f;
        }
        __syncthreads();
    }
}

extern "C" void kernel_launch(void* const* d_in, const int* in_sizes, int n_in,
                              void* d_out, int out_size, void* d_ws, size_t ws_size,
                              hipStream_t stream) {
    const float* emb  = (const float*)d_in[0];
    const float* wvec = (const float*)d_in[1];
    const int V = in_sizes[0] / D;

    int RA = RA_ROWS;
    if (RA > V) RA = V;

    float* score  = (float*)d_ws;
    float* cand_v = score + V;
    int*   cand_i = (int*)(cand_v + NCAND);

    cos_all<<<NBLOCKS, 256, 0, stream>>>(emb, wvec, score, V, NGROUPS, RA);
    block_topk<<<P2_BLOCKS, P2_THREADS, 0, stream>>>(score, V, cand_v, cand_i);
    final_topk<<<1, P2_THREADS, 0, stream>>>(cand_v, cand_i, (float*)d_out);
}